// Round 1
// baseline (338.303 us; speedup 1.0000x reference)
//
#include <hip/hip_runtime.h>
#include <climits>

#define H_   512
#define W_   512
#define C_   80
#define HW_  (H_ * W_)           // 262144 = 2^18
#define NTOT (C_ * HW_)          // 20,971,520
#define K_   10
#define NB_  1024                // stage-1 blocks (80 KB workspace)

// ---------------------------------------------------------------------------
// Stage 1: NMS-masked score + per-block top-10
// ---------------------------------------------------------------------------
__global__ __launch_bounds__(256) void stage1_topk(const float* __restrict__ kp,
                                                   float* __restrict__ wv,
                                                   int*   __restrict__ wi)
{
    float tv[K_];
    int   ti[K_];
#pragma unroll
    for (int k = 0; k < K_; ++k) { tv[k] = -1.0f; ti[k] = INT_MAX; }

    const int tid = blockIdx.x * blockDim.x + threadIdx.x;
    const int nth = gridDim.x * blockDim.x;

    for (int idx = tid; idx < NTOT; idx += nth) {
        const int cls = idx >> 18;            // idx / HW_
        const int sp  = idx & (HW_ - 1);      // spatial = y*W + x
        const int y   = sp >> 9;
        const int x   = sp & (W_ - 1);

        const float* plane = kp + (cls << 18);
        const float v = plane[sp];

        // 3x3 SAME-padded window max (border-clamped by skipping OOB)
        float wmax = v;
        const int y0 = (y > 0)      ? y - 1 : 0;
        const int y1 = (y < H_ - 1) ? y + 1 : H_ - 1;
        const int x0 = (x > 0)      ? x - 1 : 0;
        const int x1 = (x < W_ - 1) ? x + 1 : W_ - 1;
        for (int yy = y0; yy <= y1; ++yy) {
            const float* row = plane + (yy << 9);
            for (int xx = x0; xx <= x1; ++xx)
                wmax = fmaxf(wmax, row[xx]);
        }
        const float s = (v == wmax) ? v : 0.0f;   // b = keypoint * keep

        // reference flat index: (y*W + x)*C + cls
        if (s > tv[K_ - 1] ||
            (s == tv[K_ - 1] && sp * C_ + cls < ti[K_ - 1])) {
            const int ridx = sp * C_ + cls;
            int j = K_ - 1;
            while (j > 0 && (s > tv[j - 1] ||
                             (s == tv[j - 1] && ridx < ti[j - 1]))) {
                tv[j] = tv[j - 1];
                ti[j] = ti[j - 1];
                --j;
            }
            tv[j] = s;
            ti[j] = ridx;
        }
    }

    // ---- block reduction: merge sorted 10-lists pairwise -------------------
    __shared__ float sv[256][K_];
    __shared__ int   si[256][K_];
    const int t = threadIdx.x;
#pragma unroll
    for (int k = 0; k < K_; ++k) { sv[t][k] = tv[k]; si[t][k] = ti[k]; }
    __syncthreads();

    for (int stride = 128; stride > 0; stride >>= 1) {
        if (t < stride) {
            float mv[K_]; int mi[K_];
            int a = 0, b = 0;
#pragma unroll
            for (int k = 0; k < K_; ++k) {
                const float va = sv[t][a],          vb = sv[t + stride][b];
                const int   ia = si[t][a],          ib = si[t + stride][b];
                const bool takeA = (va > vb) || (va == vb && ia <= ib);
                if (takeA) { mv[k] = va; mi[k] = ia; ++a; }
                else       { mv[k] = vb; mi[k] = ib; ++b; }
            }
#pragma unroll
            for (int k = 0; k < K_; ++k) { sv[t][k] = mv[k]; si[t][k] = mi[k]; }
        }
        __syncthreads();
    }

    if (t == 0) {
#pragma unroll
        for (int k = 0; k < K_; ++k) {
            wv[blockIdx.x * K_ + k] = sv[0][k];
            wi[blockIdx.x * K_ + k] = si[0][k];
        }
    }
}

// ---------------------------------------------------------------------------
// Stage 2: reduce per-block candidates -> final top-10 -> decode boxes
// ---------------------------------------------------------------------------
__global__ __launch_bounds__(256) void stage2_final(const float* __restrict__ wv,
                                                    const int*   __restrict__ wi,
                                                    int nent,
                                                    const float* __restrict__ off,
                                                    const float* __restrict__ sz,
                                                    float* __restrict__ out)
{
    float tv[K_];
    int   ti[K_];
#pragma unroll
    for (int k = 0; k < K_; ++k) { tv[k] = -1.0f; ti[k] = INT_MAX; }

    for (int i = threadIdx.x; i < nent; i += 256) {
        const float s   = wv[i];
        const int  ridx = wi[i];
        if (s > tv[K_ - 1] || (s == tv[K_ - 1] && ridx < ti[K_ - 1])) {
            int j = K_ - 1;
            while (j > 0 && (s > tv[j - 1] ||
                             (s == tv[j - 1] && ridx < ti[j - 1]))) {
                tv[j] = tv[j - 1];
                ti[j] = ti[j - 1];
                --j;
            }
            tv[j] = s;
            ti[j] = ridx;
        }
    }

    __shared__ float sv[256][K_];
    __shared__ int   si[256][K_];
    const int t = threadIdx.x;
#pragma unroll
    for (int k = 0; k < K_; ++k) { sv[t][k] = tv[k]; si[t][k] = ti[k]; }
    __syncthreads();

    for (int stride = 128; stride > 0; stride >>= 1) {
        if (t < stride) {
            float mv[K_]; int mi[K_];
            int a = 0, b = 0;
#pragma unroll
            for (int k = 0; k < K_; ++k) {
                const float va = sv[t][a],          vb = sv[t + stride][b];
                const int   ia = si[t][a],          ib = si[t + stride][b];
                const bool takeA = (va > vb) || (va == vb && ia <= ib);
                if (takeA) { mv[k] = va; mi[k] = ia; ++a; }
                else       { mv[k] = vb; mi[k] = ib; ++b; }
            }
#pragma unroll
            for (int k = 0; k < K_; ++k) { sv[t][k] = mv[k]; si[t][k] = mi[k]; }
        }
        __syncthreads();
    }

    if (t < K_) {
        const float score = sv[0][t];
        const int   index = si[0][t];
        const int   chan  = index / C_;          // y*W + x
        const int   cls   = index - chan * C_;
        const int   y     = chan >> 9;
        const int   x     = chan & (W_ - 1);

        // offsets/sizes with last-dim flip: col0 <- channel1, col1 <- channel0
        const float offy = off[HW_ + chan];   // channel 1
        const float offx = off[chan];         // channel 0
        const float szy  = sz[HW_ + chan];
        const float szx  = sz[chan];

        const float py = (float)y + offy;
        const float px = (float)x + offx;
        const float hy = 0.5f * szy;
        const float hx = 0.5f * szx;

        const float lo = 0.0f, hi = (float)(W_ - 1);
        const float b0 = fminf(fmaxf(py - hy, lo), hi) * 4.0f;
        const float b1 = fminf(fmaxf(px - hx, lo), hi) * 4.0f;
        const float b2 = fminf(fmaxf(py + hy, lo), hi) * 4.0f;
        const float b3 = fminf(fmaxf(px + hx, lo), hi) * 4.0f;

        out[t * 4 + 0] = b0;
        out[t * 4 + 1] = b1;
        out[t * 4 + 2] = b2;
        out[t * 4 + 3] = b3;
        out[40 + t]    = (float)cls;   // detection_classes
        out[50 + t]    = score;        // detection_scores
    }
}

// ---------------------------------------------------------------------------
extern "C" void kernel_launch(void* const* d_in, const int* in_sizes, int n_in,
                              void* d_out, int out_size, void* d_ws, size_t ws_size,
                              hipStream_t stream)
{
    const float* off = (const float*)d_in[0];   // [1,2,512,512]
    const float* sz  = (const float*)d_in[1];   // [1,2,512,512]
    const float* kp  = (const float*)d_in[2];   // [1,80,512,512]
    float* out = (float*)d_out;                 // 40 + 10 + 10 = 60 floats

    int nb = NB_;
    const size_t need_per_block = (size_t)K_ * 8;     // 10*(float+int)
    if (ws_size < (size_t)nb * need_per_block) {
        nb = (int)(ws_size / need_per_block);
        if (nb < 1) nb = 1;
    }

    float* wv = (float*)d_ws;
    int*   wi = (int*)((char*)d_ws + (size_t)nb * K_ * sizeof(float));

    stage1_topk<<<nb, 256, 0, stream>>>(kp, wv, wi);
    stage2_final<<<1, 256, 0, stream>>>(wv, wi, nb * K_, off, sz, out);
}

// Round 2
// 193.720 us; speedup vs baseline: 1.7463x; 1.7463x over previous
//
#include <hip/hip_runtime.h>
#include <climits>
#include <float.h>

#define H_     512
#define W_     512
#define C_     80
#define HW_    (H_ * W_)           // 262144 = 2^18
#define NTOT   (C_ * HW_)          // 20,971,520
#define NCHUNK (NTOT / 4)          // 5,242,880 float4 chunks
#define K_     10
#define NB_    2048                // stage-1 blocks (160 KB workspace)

__device__ __forceinline__ float max3f(float a, float b, float c) {
    return fmaxf(fmaxf(a, b), c);
}

// Bubble-insert (s, ridx) into descending sorted (tv, ti).
// Fully unrolled, compile-time indices only -> stays in VGPRs (rule #20).
__device__ __forceinline__ void insert10(float (&tv)[K_], int (&ti)[K_],
                                         float s, int ridx) {
#pragma unroll
    for (int j = 0; j < K_; ++j) {
        const bool better = (s > tv[j]) || (s == tv[j] && ridx < ti[j]);
        const float ov = tv[j]; const int oi = ti[j];
        if (better) { tv[j] = s; ti[j] = ridx; s = ov; ridx = oi; }
    }
}

// ---------------------------------------------------------------------------
// Stage 1: NMS-masked score + per-block top-10.
// Each thread handles one float4 (4 pixels of one class-plane row) per iter.
// All 9 loads per iteration are independent -> single latency window.
// ---------------------------------------------------------------------------
__global__ __launch_bounds__(256) void stage1_topk(const float* __restrict__ kp,
                                                   float* __restrict__ wv,
                                                   int*   __restrict__ wi)
{
    float tv[K_];
    int   ti[K_];
#pragma unroll
    for (int k = 0; k < K_; ++k) { tv[k] = -1.0f; ti[k] = INT_MAX; }
    float thresh = -1.0f;   // == tv[K_-1], kept in a register

    const int tid = blockIdx.x * 256 + threadIdx.x;
    const int nth = gridDim.x * 256;

    for (int ch = tid; ch < NCHUNK; ch += nth) {
        const int cls = ch >> 16;            // 65536 chunks per 512x512 plane
        const int spc = ch & 0xFFFF;
        const int y   = spc >> 7;            // 128 chunks per row
        const int x   = (spc & 127) << 2;

        const float* plane = kp + (cls << 18);
        const int ym1 = (y > 0)      ? y - 1 : 0;
        const int yp1 = (y < H_ - 1) ? y + 1 : H_ - 1;
        const float* ra = plane + (ym1 << 9);
        const float* rb = plane + (y   << 9);
        const float* rc = plane + (yp1 << 9);

        // 3 vector loads + 6 clamped scalar loads, all independent
        const float4 a = *(const float4*)(ra + x);
        const float4 b = *(const float4*)(rb + x);
        const float4 c = *(const float4*)(rc + x);
        const int xl = (x > 0)        ? x - 1 : 0;
        const int xr = (x + 4 < W_)   ? x + 4 : W_ - 1;
        const float la = ra[xl], lb = rb[xl], lc = rc[xl];
        const float ka = ra[xr], kb = rb[xr], kc = rc[xr];

        // vertical 3-max per column
        const float vm0 = max3f(a.x, b.x, c.x);
        const float vm1 = max3f(a.y, b.y, c.y);
        const float vm2 = max3f(a.z, b.z, c.z);
        const float vm3 = max3f(a.w, b.w, c.w);
        const float lv  = (x > 0)      ? max3f(la, lb, lc) : -FLT_MAX;
        const float rv  = (x + 4 < W_) ? max3f(ka, kb, kc) : -FLT_MAX;

        // horizontal 3-max -> full 3x3 window max
        const float w0 = fmaxf(lv, fmaxf(vm0, vm1));
        const float w1 = max3f(vm0, vm1, vm2);
        const float w2 = max3f(vm1, vm2, vm3);
        const float w3 = fmaxf(fmaxf(vm2, vm3), rv);

        const float s0 = (b.x == w0) ? b.x : 0.0f;
        const float s1 = (b.y == w1) ? b.y : 0.0f;
        const float s2 = (b.z == w2) ? b.z : 0.0f;
        const float s3 = (b.w == w3) ? b.w : 0.0f;

        const float m = fmaxf(fmaxf(s0, s1), fmaxf(s2, s3));
        if (m >= thresh) {
            const int base = ((y << 9) + x) * C_ + cls;   // ref flat index
            if (s0 >= thresh) insert10(tv, ti, s0, base);
            if (s1 >= thresh) insert10(tv, ti, s1, base + C_);
            if (s2 >= thresh) insert10(tv, ti, s2, base + 2 * C_);
            if (s3 >= thresh) insert10(tv, ti, s3, base + 3 * C_);
            thresh = tv[K_ - 1];
        }
    }

    // ---- block reduction: merge sorted 10-lists pairwise -------------------
    __shared__ float sv[256][K_];
    __shared__ int   si[256][K_];
    const int t = threadIdx.x;
#pragma unroll
    for (int k = 0; k < K_; ++k) { sv[t][k] = tv[k]; si[t][k] = ti[k]; }
    __syncthreads();

    for (int stride = 128; stride > 0; stride >>= 1) {
        if (t < stride) {
            float mv[K_]; int mi[K_];
            int a = 0, b = 0;
#pragma unroll
            for (int k = 0; k < K_; ++k) {
                const float va = sv[t][a], vb = sv[t + stride][b];
                const int   ia = si[t][a], ib = si[t + stride][b];
                const bool takeA = (va > vb) || (va == vb && ia <= ib);
                if (takeA) { mv[k] = va; mi[k] = ia; ++a; }
                else       { mv[k] = vb; mi[k] = ib; ++b; }
            }
#pragma unroll
            for (int k = 0; k < K_; ++k) { sv[t][k] = mv[k]; si[t][k] = mi[k]; }
        }
        __syncthreads();
    }

    if (t == 0) {
#pragma unroll
        for (int k = 0; k < K_; ++k) {
            wv[blockIdx.x * K_ + k] = sv[0][k];
            wi[blockIdx.x * K_ + k] = si[0][k];
        }
    }
}

// ---------------------------------------------------------------------------
// Stage 2: reduce per-block candidates -> final top-10 -> decode boxes
// ---------------------------------------------------------------------------
__global__ __launch_bounds__(256) void stage2_final(const float* __restrict__ wv,
                                                    const int*   __restrict__ wi,
                                                    int nent,
                                                    const float* __restrict__ off,
                                                    const float* __restrict__ sz,
                                                    float* __restrict__ out)
{
    float tv[K_];
    int   ti[K_];
#pragma unroll
    for (int k = 0; k < K_; ++k) { tv[k] = -1.0f; ti[k] = INT_MAX; }
    float thresh = -1.0f;

    // nent is a multiple of 4 (nb rounded to multiple of 4)
    for (int i = threadIdx.x * 4; i < nent; i += 256 * 4) {
        const float4 v  = *(const float4*)(wv + i);
        const int4   ix = *(const int4*)(wi + i);
        const float m = fmaxf(fmaxf(v.x, v.y), fmaxf(v.z, v.w));
        if (m >= thresh) {
            if (v.x >= thresh) insert10(tv, ti, v.x, ix.x);
            if (v.y >= thresh) insert10(tv, ti, v.y, ix.y);
            if (v.z >= thresh) insert10(tv, ti, v.z, ix.z);
            if (v.w >= thresh) insert10(tv, ti, v.w, ix.w);
            thresh = tv[K_ - 1];
        }
    }

    __shared__ float sv[256][K_];
    __shared__ int   si[256][K_];
    const int t = threadIdx.x;
#pragma unroll
    for (int k = 0; k < K_; ++k) { sv[t][k] = tv[k]; si[t][k] = ti[k]; }
    __syncthreads();

    for (int stride = 128; stride > 0; stride >>= 1) {
        if (t < stride) {
            float mv[K_]; int mi[K_];
            int a = 0, b = 0;
#pragma unroll
            for (int k = 0; k < K_; ++k) {
                const float va = sv[t][a], vb = sv[t + stride][b];
                const int   ia = si[t][a], ib = si[t + stride][b];
                const bool takeA = (va > vb) || (va == vb && ia <= ib);
                if (takeA) { mv[k] = va; mi[k] = ia; ++a; }
                else       { mv[k] = vb; mi[k] = ib; ++b; }
            }
#pragma unroll
            for (int k = 0; k < K_; ++k) { sv[t][k] = mv[k]; si[t][k] = mi[k]; }
        }
        __syncthreads();
    }

    if (t < K_) {
        const float score = sv[0][t];
        const int   index = si[0][t];
        const int   chan  = index / C_;          // y*W + x
        const int   cls   = index - chan * C_;
        const int   y     = chan >> 9;
        const int   x     = chan & (W_ - 1);

        // offsets/sizes with last-dim flip: y-comp <- channel1, x-comp <- channel0
        const float offy = off[HW_ + chan];   // channel 1
        const float offx = off[chan];         // channel 0
        const float szy  = sz[HW_ + chan];
        const float szx  = sz[chan];

        const float py = (float)y + offy;
        const float px = (float)x + offx;
        const float hy = 0.5f * szy;
        const float hx = 0.5f * szx;

        const float lo = 0.0f, hi = (float)(W_ - 1);
        out[t * 4 + 0] = fminf(fmaxf(py - hy, lo), hi) * 4.0f;
        out[t * 4 + 1] = fminf(fmaxf(px - hx, lo), hi) * 4.0f;
        out[t * 4 + 2] = fminf(fmaxf(py + hy, lo), hi) * 4.0f;
        out[t * 4 + 3] = fminf(fmaxf(px + hx, lo), hi) * 4.0f;
        out[40 + t]    = (float)cls;   // detection_classes
        out[50 + t]    = score;        // detection_scores
    }
}

// ---------------------------------------------------------------------------
extern "C" void kernel_launch(void* const* d_in, const int* in_sizes, int n_in,
                              void* d_out, int out_size, void* d_ws, size_t ws_size,
                              hipStream_t stream)
{
    const float* off = (const float*)d_in[0];   // [1,2,512,512]
    const float* sz  = (const float*)d_in[1];   // [1,2,512,512]
    const float* kp  = (const float*)d_in[2];   // [1,80,512,512]
    float* out = (float*)d_out;                 // 40 + 10 + 10 = 60 floats

    int nb = NB_;
    const size_t need_per_block = (size_t)K_ * 8;     // 10*(float+int)
    if (ws_size < (size_t)nb * need_per_block) {
        nb = (int)(ws_size / need_per_block) & ~3;    // keep nent % 4 == 0
        if (nb < 4) nb = 4;
    }

    float* wv = (float*)d_ws;
    int*   wi = (int*)((char*)d_ws + (size_t)nb * K_ * sizeof(float));

    stage1_topk<<<nb, 256, 0, stream>>>(kp, wv, wi);
    stage2_final<<<1, 256, 0, stream>>>(wv, wi, nb * K_, off, sz, out);
}

// Round 3
// 59.747 us; speedup vs baseline: 5.6622x; 3.2423x over previous
//
#include <hip/hip_runtime.h>
#include <climits>
#include <float.h>

#define H_     512
#define W_     512
#define C_     80
#define HW_    (H_ * W_)           // 262144 = 2^18
#define NTOT   (C_ * HW_)          // 20,971,520
#define NCHUNK (NTOT / 4)          // 5,242,880 float4 chunks
#define K_     10
#define NB_    2048                // scan blocks
#define TAU    0.9999f             // candidate threshold (validity re-checked)

__device__ __forceinline__ float max3f(float a, float b, float c) {
    return fmaxf(fmaxf(a, b), c);
}

// Fully-unrolled bubble insert into descending sorted (tv, ti), tie -> lower idx.
__device__ __forceinline__ void insert10(float (&tv)[K_], int (&ti)[K_],
                                         float s, int ridx) {
#pragma unroll
    for (int j = 0; j < K_; ++j) {
        const bool better = (s > tv[j]) || (s == tv[j] && ridx < ti[j]);
        const float ov = tv[j]; const int oi = ti[j];
        if (better) { tv[j] = s; ti[j] = ridx; s = ov; ridx = oi; }
    }
}

// ---------------------------------------------------------------------------
// k_init: zero the candidate counter
// ---------------------------------------------------------------------------
__global__ void k_init(int* cnt) { if (threadIdx.x == 0) *cnt = 0; }

// ---------------------------------------------------------------------------
// k_scan: NMS-masked score; append (score,index) when score > TAU.
// Hot path is pure stencil — append branch is taken in ~2.5% of wave-iters.
// ---------------------------------------------------------------------------
__global__ __launch_bounds__(256) void k_scan(const float* __restrict__ kp,
                                              float* __restrict__ cs,
                                              int*   __restrict__ cidx,
                                              int*   __restrict__ cnt,
                                              int cap)
{
    const int tid = blockIdx.x * 256 + threadIdx.x;
    const int nth = gridDim.x * 256;

    for (int ch = tid; ch < NCHUNK; ch += nth) {
        const int cls = ch >> 16;            // 65536 chunks per plane
        const int spc = ch & 0xFFFF;         // chunk within plane; pixel = spc*4
        const int y   = spc >> 7;
        const int x   = (spc & 127) << 2;

        const float* plane = kp + (cls << 18);
        const int ym1 = (y > 0)      ? y - 1 : 0;
        const int yp1 = (y < H_ - 1) ? y + 1 : H_ - 1;
        const float* ra = plane + (ym1 << 9);
        const float* rb = plane + (y   << 9);
        const float* rc = plane + (yp1 << 9);

        const float4 a = *(const float4*)(ra + x);
        const float4 b = *(const float4*)(rb + x);
        const float4 c = *(const float4*)(rc + x);
        const int xl = (x > 0)      ? x - 1 : 0;
        const int xr = (x + 4 < W_) ? x + 4 : W_ - 1;
        const float la = ra[xl], lb = rb[xl], lc = rc[xl];
        const float ka = ra[xr], kb = rb[xr], kc = rc[xr];

        // cheap pre-filter on raw values: a kept score equals its raw value
        if (__builtin_expect((b.x > TAU) | (b.y > TAU) | (b.z > TAU) | (b.w > TAU), 0)) {
            const float vm0 = max3f(a.x, b.x, c.x);
            const float vm1 = max3f(a.y, b.y, c.y);
            const float vm2 = max3f(a.z, b.z, c.z);
            const float vm3 = max3f(a.w, b.w, c.w);
            const float lv  = (x > 0)      ? max3f(la, lb, lc) : -FLT_MAX;
            const float rv  = (x + 4 < W_) ? max3f(ka, kb, kc) : -FLT_MAX;

            const float w0 = fmaxf(lv, fmaxf(vm0, vm1));
            const float w1 = max3f(vm0, vm1, vm2);
            const float w2 = max3f(vm1, vm2, vm3);
            const float w3 = fmaxf(fmaxf(vm2, vm3), rv);

            const int base = spc * (4 * C_) + cls;    // ((y*W+x)*C + cls)
            if (b.x > TAU && b.x == w0) {
                const int p = atomicAdd(cnt, 1);
                if (p < cap) { cs[p] = b.x; cidx[p] = base; }
            }
            if (b.y > TAU && b.y == w1) {
                const int p = atomicAdd(cnt, 1);
                if (p < cap) { cs[p] = b.y; cidx[p] = base + C_; }
            }
            if (b.z > TAU && b.z == w2) {
                const int p = atomicAdd(cnt, 1);
                if (p < cap) { cs[p] = b.z; cidx[p] = base + 2 * C_; }
            }
            if (b.w > TAU && b.w == w3) {
                const int p = atomicAdd(cnt, 1);
                if (p < cap) { cs[p] = b.w; cidx[p] = base + 3 * C_; }
            }
        }
    }
}

// ---------------------------------------------------------------------------
// k_reduce: single block. If candidate list is valid (count in [10, cap]),
// top-10 comes from the list (guaranteed superset of global top-10, since the
// 10th-best masked score must exceed TAU when >=10 scores exceed TAU).
// Otherwise: exhaustive fallback scan (correct for arbitrary input).
// Then decode boxes.
// ---------------------------------------------------------------------------
__global__ __launch_bounds__(256) void k_reduce(const float* __restrict__ cs,
                                                const int*   __restrict__ cidx,
                                                const int*   __restrict__ cnt,
                                                int cap,
                                                const float* __restrict__ kp,
                                                const float* __restrict__ off,
                                                const float* __restrict__ sz,
                                                float* __restrict__ out)
{
    float tv[K_];
    int   ti[K_];
#pragma unroll
    for (int k = 0; k < K_; ++k) { tv[k] = 0.0f; ti[k] = INT_MAX; }

    const int n = *cnt;
    const bool valid = (n >= K_) && (n <= cap);

    if (valid) {
        for (int i = threadIdx.x; i < n; i += 256)
            insert10(tv, ti, cs[i], cidx[i]);
    } else {
        // exhaustive fallback (never taken for the benchmark input)
        float thresh = 0.0f;
        for (int idx = threadIdx.x; idx < NTOT; idx += 256) {
            const int cls = idx >> 18;
            const int sp  = idx & (HW_ - 1);
            const int y   = sp >> 9;
            const int x   = sp & (W_ - 1);
            const float* plane = kp + (cls << 18);
            const float v = plane[sp];
            float wmax = v;
            const int y0 = (y > 0)      ? y - 1 : 0;
            const int y1 = (y < H_ - 1) ? y + 1 : H_ - 1;
            const int x0 = (x > 0)      ? x - 1 : 0;
            const int x1 = (x < W_ - 1) ? x + 1 : W_ - 1;
            for (int yy = y0; yy <= y1; ++yy)
                for (int xx = x0; xx <= x1; ++xx)
                    wmax = fmaxf(wmax, plane[(yy << 9) + xx]);
            if (v == wmax && v > thresh) {
                insert10(tv, ti, v, sp * C_ + cls);
                thresh = tv[K_ - 1];
            }
        }
    }

    // ---- block merge of sorted 10-lists ------------------------------------
    __shared__ float sv[256][K_];
    __shared__ int   si[256][K_];
    const int t = threadIdx.x;
#pragma unroll
    for (int k = 0; k < K_; ++k) { sv[t][k] = tv[k]; si[t][k] = ti[k]; }
    __syncthreads();

    for (int stride = 128; stride > 0; stride >>= 1) {
        if (t < stride) {
            float mv[K_]; int mi[K_];
            int a = 0, b = 0;
#pragma unroll
            for (int k = 0; k < K_; ++k) {
                const float va = sv[t][a], vb = sv[t + stride][b];
                const int   ia = si[t][a], ib = si[t + stride][b];
                const bool takeA = (va > vb) || (va == vb && ia <= ib);
                if (takeA) { mv[k] = va; mi[k] = ia; ++a; }
                else       { mv[k] = vb; mi[k] = ib; ++b; }
            }
#pragma unroll
            for (int k = 0; k < K_; ++k) { sv[t][k] = mv[k]; si[t][k] = mi[k]; }
        }
        __syncthreads();
    }

    if (t < K_) {
        const float score = sv[0][t];
        const int   index = si[0][t];
        const int   chan  = index / C_;          // y*W + x
        const int   cls   = index - chan * C_;
        const int   y     = chan >> 9;
        const int   x     = chan & (W_ - 1);

        // last-dim flip: y-component <- channel 1, x-component <- channel 0
        const float offy = off[HW_ + chan];
        const float offx = off[chan];
        const float szy  = sz[HW_ + chan];
        const float szx  = sz[chan];

        const float py = (float)y + offy;
        const float px = (float)x + offx;
        const float hy = 0.5f * szy;
        const float hx = 0.5f * szx;

        const float lo = 0.0f, hi = (float)(W_ - 1);
        out[t * 4 + 0] = fminf(fmaxf(py - hy, lo), hi) * 4.0f;
        out[t * 4 + 1] = fminf(fmaxf(px - hx, lo), hi) * 4.0f;
        out[t * 4 + 2] = fminf(fmaxf(py + hy, lo), hi) * 4.0f;
        out[t * 4 + 3] = fminf(fmaxf(px + hx, lo), hi) * 4.0f;
        out[40 + t]    = (float)cls;   // detection_classes
        out[50 + t]    = score;        // detection_scores
    }
}

// ---------------------------------------------------------------------------
extern "C" void kernel_launch(void* const* d_in, const int* in_sizes, int n_in,
                              void* d_out, int out_size, void* d_ws, size_t ws_size,
                              hipStream_t stream)
{
    const float* off = (const float*)d_in[0];   // [1,2,512,512]
    const float* sz  = (const float*)d_in[1];   // [1,2,512,512]
    const float* kp  = (const float*)d_in[2];   // [1,80,512,512]
    float* out = (float*)d_out;                 // 40 + 10 + 10 = 60 floats

    // ws layout: [0..15] counter (16B aligned pad) | cs[cap] floats | cidx[cap] ints
    int cap = 8192;
    const size_t avail = (ws_size > 16) ? (ws_size - 16) : 0;
    if ((size_t)cap * 8 > avail) cap = (int)(avail / 8);
    if (cap < 16) cap = 16;

    int*   cnt  = (int*)d_ws;
    float* cs   = (float*)((char*)d_ws + 16);
    int*   cidx = (int*)((char*)d_ws + 16 + (size_t)cap * sizeof(float));

    k_init<<<1, 64, 0, stream>>>(cnt);
    k_scan<<<NB_, 256, 0, stream>>>(kp, cs, cidx, cnt, cap);
    k_reduce<<<1, 256, 0, stream>>>(cs, cidx, cnt, cap, kp, off, sz, out);
}